// Round 5
// baseline (208.821 us; speedup 1.0000x reference)
//
#include <hip/hip_runtime.h>

// SharedGroupLinearLayer R7.
// R6 post-mortem: plain stores kept WRITE at 93.7MB (NT: 95.5) -> NT theory
// dead. FETCH rose 39->46MB with plain stores -> write-allocate RMW on
// partial-line stores: each store instr writes 16 scattered 64-B half-lines
// (col*256 + ot*64 + q*16). Full-line writers (fill, m13 copy) hit 6.3-6.5
// TB/s; we sit at 2.9. Store pattern is the invariant across R4/R5b/R6.
// R7: transpose acc frags through a per-wave 4KB LDS tile (XOR slot swizzle,
// conflict-free both sides), then store contiguous 1KB per instruction =
// 8 full 128-B lines. LDS 32KB/block -> 5 blocks/CU exact, grid 1280 (one
// generation, 20 waves/CU), 3-4 tiles/wave, depth-2 rotation.
//
// out[n,o] = (X w1^T + b1) + att0 * (X (w0-w1)^T + (b0-b1)),
// att0 = sigmoid(l0-l1); emb folded into acc init: C0 = b + E·W^T.

#define NBLK   1280                // 5 blocks/CU exactly (LDS 32KB x 5 = 160KB)
#define WAVES  (NBLK * 4)          // 5120
#define NTILES 16384               // 262144 tokens / 16 per tile

typedef short bf16x8 __attribute__((ext_vector_type(8)));
typedef float f32x4  __attribute__((ext_vector_type(4)));

union B8 { bf16x8 v; unsigned u[4]; };

__device__ __forceinline__ unsigned pk2bf(float lo, float hi) {
    unsigned a = __float_as_uint(lo) + 0x8000u;
    unsigned b = __float_as_uint(hi) + 0x8000u;
    return __builtin_amdgcn_perm(b, a, 0x07060302u);
}

__device__ __forceinline__ void pack8(B8& d, float4 p, float4 q) {
    d.u[0] = pk2bf(p.x, p.y); d.u[1] = pk2bf(p.z, p.w);
    d.u[2] = pk2bf(q.x, q.y); d.u[3] = pk2bf(q.z, q.w);
}

__global__ __launch_bounds__(256, 5) void sgll_kernel(
    const float* __restrict__ x,    // (262144, 64)
    const float* __restrict__ emb,  // (16, 64)  row = token % 16
    const float* __restrict__ rw,   // (64, 2)
    const float* __restrict__ ws,   // (2, 64, 64) w_stack[t][o][d]
    const float* __restrict__ bs,   // (2, 64)
    float* __restrict__ out)        // (262144, 64)
{
    __shared__ bf16x8 sW1[8][64];   // [kt*4+ot][lane]  w1 A-frags   (8KB)
    __shared__ bf16x8 sWd[8][64];   // w0-w1 A-frags                 (8KB)
    __shared__ float  sOut[4][1024]; // per-wave store-transpose tile (16KB)

    const int tid  = threadIdx.x;
    const int lane = tid & 63;
    const int wv   = tid >> 6;
    const int col  = lane & 15;
    const int q    = lane >> 4;

    // ---- setup: stage W frags (waves split the 8 (kt,ot) combos) ----
    #pragma unroll
    for (int c = wv; c < 8; c += 4) {
        const int kt = c >> 2, ot = c & 3;
        const float* p0 = ws + (ot * 16 + col) * 64 + kt * 32 + q * 8;  // w0
        const float* p1 = p0 + 4096;                                    // w1
        float4 a0 = *(const float4*)p0, a1 = *(const float4*)(p0 + 4);
        float4 c0 = *(const float4*)p1, c1 = *(const float4*)(p1 + 4);
        B8 f1, fd;
        pack8(f1, c0, c1);
        fd.u[0] = pk2bf(a0.x - c0.x, a0.y - c0.y);
        fd.u[1] = pk2bf(a0.z - c0.z, a0.w - c0.w);
        fd.u[2] = pk2bf(a1.x - c1.x, a1.y - c1.y);
        fd.u[3] = pk2bf(a1.z - c1.z, a1.w - c1.w);
        sW1[c][lane] = f1.v;
        sWd[c][lane] = fd.v;
    }

    // ---- R frags (regs), duplicated across row parity:
    // A[m][k] = rw[k][m&1] -> C rows 4q+0 / 4q+1 = (l0, l1) on EVERY lane.
    B8 R0, R1;
    {
        const int c01 = col & 1;
        float v[8];
        #pragma unroll
        for (int j = 0; j < 8; ++j)
            v[j] = rw[(q * 8 + j) * 2 + c01];
        pack8(R0, make_float4(v[0], v[1], v[2], v[3]), make_float4(v[4], v[5], v[6], v[7]));
        #pragma unroll
        for (int j = 0; j < 8; ++j)
            v[j] = rw[(32 + q * 8 + j) * 2 + c01];
        pack8(R1, make_float4(v[0], v[1], v[2], v[3]), make_float4(v[4], v[5], v[6], v[7]));
    }

    // ---- E frags + bias combos (regs, per wave) ----
    B8 E0, E1;
    {
        const float* ep = emb + col * 64 + q * 8;
        pack8(E0, *(const float4*)ep, *(const float4*)(ep + 4));
        pack8(E1, *(const float4*)(ep + 32), *(const float4*)(ep + 36));
    }
    f32x4 bI1[4], bId[4];
    #pragma unroll
    for (int ot = 0; ot < 4; ++ot) {
        float4 b1 = *(const float4*)(bs + 64 + ot * 16 + q * 4);
        float4 b0 = *(const float4*)(bs + ot * 16 + q * 4);
        bI1[ot][0] = b1.x; bI1[ot][1] = b1.y; bI1[ot][2] = b1.z; bI1[ot][3] = b1.w;
        bId[ot][0] = b0.x - b1.x; bId[ot][1] = b0.y - b1.y;
        bId[ot][2] = b0.z - b1.z; bId[ot][3] = b0.w - b1.w;
    }

    __syncthreads();  // W frags ready

    const int w = blockIdx.x * 4 + wv;   // wave id, 0..5119
    float* const sO = &sOut[wv][0];      // this wave's 4KB staging tile

    // LDS transpose addresses (floats), slot-swizzled: slot' = slot ^ col.
    // write (per ot): logical byte col*256 + ((ot*4+q)^col... slot=ot*4+q
    int wo0 = col * 64 + (((0 * 4 + q) ^ col) << 2);
    int wo1 = col * 64 + (((1 * 4 + q) ^ col) << 2);
    int wo2 = col * 64 + (((2 * 4 + q) ^ col) << 2);
    int wo3 = col * 64 + (((3 * 4 + q) ^ col) << 2);
    // read (per store instr k): row = k*4+q; slot = col ^ row
    int ro0 = (0 * 4 + q) * 64 + ((col ^ (0 * 4 + q)) << 2);
    int ro1 = (1 * 4 + q) * 64 + ((col ^ (1 * 4 + q)) << 2);
    int ro2 = (2 * 4 + q) * 64 + ((col ^ (2 * 4 + q)) << 2);
    int ro3 = (3 * 4 + q) * 64 + ((col ^ (3 * 4 + q)) << 2);

    auto loadt = [&](float4 (&B)[4], int T) {
        const float* p = x + ((long)T * 16 + col) * 64 + q * 8;
        B[0] = *(const float4*)p;        B[1] = *(const float4*)(p + 4);
        B[2] = *(const float4*)(p + 32); B[3] = *(const float4*)(p + 36);
    };

    // ---- prologue: depth-2 pipeline ----
    float4 bA[4], bB[4];
    loadt(bA, w);
    loadt(bB, w + WAVES);
    __builtin_amdgcn_sched_barrier(0);   // pin the burst before compute

    // ---- acc init via MFMA (overlaps prologue load latency) ----
    f32x4 I1[4], Id[4], Il;
    #pragma unroll
    for (int ot = 0; ot < 4; ++ot) {
        f32x4 a1 = bI1[ot], ad = bId[ot];
        a1 = __builtin_amdgcn_mfma_f32_16x16x32_bf16(sW1[ot][lane],     E0.v, a1, 0, 0, 0);
        a1 = __builtin_amdgcn_mfma_f32_16x16x32_bf16(sW1[4 + ot][lane], E1.v, a1, 0, 0, 0);
        ad = __builtin_amdgcn_mfma_f32_16x16x32_bf16(sWd[ot][lane],     E0.v, ad, 0, 0, 0);
        ad = __builtin_amdgcn_mfma_f32_16x16x32_bf16(sWd[4 + ot][lane], E1.v, ad, 0, 0, 0);
        I1[ot] = a1;
        Id[ot] = ad;
    }
    {
        f32x4 z = {0.f, 0.f, 0.f, 0.f};
        z = __builtin_amdgcn_mfma_f32_16x16x32_bf16(R0.v, E0.v, z, 0, 0, 0);
        z = __builtin_amdgcn_mfma_f32_16x16x32_bf16(R1.v, E1.v, z, 0, 0, 0);
        Il = z;
    }

    auto step = [&](float4 (&B)[4], int TI, bool refill, int RT) {
        B8 X0, X1;
        pack8(X0, B[0], B[1]);
        pack8(X1, B[2], B[3]);
        if (refill) loadt(B, RT);   // loads precede this step's stores

        f32x4 lac = Il;
        lac = __builtin_amdgcn_mfma_f32_16x16x32_bf16(R0.v, X0.v, lac, 0, 0, 0);
        lac = __builtin_amdgcn_mfma_f32_16x16x32_bf16(R1.v, X1.v, lac, 0, 0, 0);
        // rows 4q+0 / 4q+1 hold (l0, l1) on every lane -> no shuffle
        const float att = 1.0f / (1.0f + __expf(lac[1] - lac[0]));

        // compute + stage into LDS (transpose to store layout)
        #pragma unroll
        for (int ot = 0; ot < 4; ++ot) {
            f32x4 y = I1[ot];
            y = __builtin_amdgcn_mfma_f32_16x16x32_bf16(sW1[ot][lane],     X0.v, y, 0, 0, 0);
            y = __builtin_amdgcn_mfma_f32_16x16x32_bf16(sW1[4 + ot][lane], X1.v, y, 0, 0, 0);
            f32x4 d = Id[ot];
            d = __builtin_amdgcn_mfma_f32_16x16x32_bf16(sWd[ot][lane],     X0.v, d, 0, 0, 0);
            d = __builtin_amdgcn_mfma_f32_16x16x32_bf16(sWd[4 + ot][lane], X1.v, d, 0, 0, 0);
            f32x4 o;
            o[0] = fmaf(att, d[0], y[0]);
            o[1] = fmaf(att, d[1], y[1]);
            o[2] = fmaf(att, d[2], y[2]);
            o[3] = fmaf(att, d[3], y[3]);
            const int wo = (ot == 0) ? wo0 : (ot == 1) ? wo1 : (ot == 2) ? wo2 : wo3;
            *(f32x4*)(sO + wo) = o;
        }

        // read back in store layout; each global store = contiguous 1KB
        // (8 full 128-B lines) -> no partial-line RMW at L2.
        f32x4 s0 = *(const f32x4*)(sO + ro0);
        f32x4 s1 = *(const f32x4*)(sO + ro1);
        f32x4 s2 = *(const f32x4*)(sO + ro2);
        f32x4 s3 = *(const f32x4*)(sO + ro3);
        float* gp = out + (long)TI * 1024 + lane * 4;
        *(f32x4*)(gp)       = s0;
        *(f32x4*)(gp + 256) = s1;
        *(f32x4*)(gp + 512) = s2;
        *(f32x4*)(gp + 768) = s3;
    };

    // tiles per wave: 3 for all, +1 for waves w < NTILES - 3*WAVES (=1024)
    const bool four = (w < NTILES - 3 * WAVES);

    step(bA, w,             true, w + 2 * WAVES);   // refill valid (max 15359)
    step(bB, w +     WAVES, four, w + 3 * WAVES);
    step(bA, w + 2 * WAVES, false, 0);
    if (four)
        step(bB, w + 3 * WAVES, false, 0);
}

extern "C" void kernel_launch(void* const* d_in, const int* in_sizes, int n_in,
                              void* d_out, int out_size, void* d_ws, size_t ws_size,
                              hipStream_t stream) {
    const float* x   = (const float*)d_in[0];
    const float* emb = (const float*)d_in[1];
    const float* rw  = (const float*)d_in[2];
    const float* wsk = (const float*)d_in[3];
    const float* bs  = (const float*)d_in[4];
    float* out = (float*)d_out;
    sgll_kernel<<<NBLK, 256, 0, stream>>>(x, emb, rw, wsk, bs, out);
}

// Round 6
// 184.144 us; speedup vs baseline: 1.1340x; 1.1340x over previous
//
#include <hip/hip_runtime.h>

// SharedGroupLinearLayer R8.
// R7 post-mortem: VGPR 84->48 + SGPR 112 = compiler moved arrays to
// SCRATCH; hbm_bytes 380MB (scratch traffic). Store-transpose theory never
// tested. Also re-read R6: FETCH 46<67 + WRITE 94>67 are poison-fill L3
// residue (input hot in L3, fill's dirty lines draining in our window) --
// the write-amplification was attributional. Real mystery: true traffic
// ~134MB = 21us floor, we take 49us, with per-wave vmcnt serialization
// (stores share the vmcnt queue with loads -> each step's consume-wait
// drains stores too) and low load-outstanding duty cycle.
// R8: ONE tile per wave, 4096 blocks. x-loads issued FIRST (latency hides
// under W-staging+sync), then setup, acc-init, consume, 4 stores, die.
// No store->load wait chain in any wave; 6-8 blocks/CU resident out of
// 4096 -> continuous churn of fresh load bursts (how the fill kernel
// sustains 6.5 TB/s).
//
// out[n,o] = (X w1^T + b1) + att0 * (X (w0-w1)^T + (b0-b1)),
// att0 = sigmoid(l0-l1); emb folded into acc init: C0 = b + E·W^T.

#define NBLK 4096   // x 4 waves x 16 tokens = 262144

typedef short bf16x8 __attribute__((ext_vector_type(8)));
typedef float f32x4  __attribute__((ext_vector_type(4)));

union B8 { bf16x8 v; unsigned u[4]; };

__device__ __forceinline__ unsigned pk2bf(float lo, float hi) {
    unsigned a = __float_as_uint(lo) + 0x8000u;
    unsigned b = __float_as_uint(hi) + 0x8000u;
    return __builtin_amdgcn_perm(b, a, 0x07060302u);
}

__device__ __forceinline__ void pack8(B8& d, float4 p, float4 q) {
    d.u[0] = pk2bf(p.x, p.y); d.u[1] = pk2bf(p.z, p.w);
    d.u[2] = pk2bf(q.x, q.y); d.u[3] = pk2bf(q.z, q.w);
}

__global__ __launch_bounds__(256, 6) void sgll_kernel(
    const float* __restrict__ x,    // (262144, 64)
    const float* __restrict__ emb,  // (16, 64)  row = token % 16
    const float* __restrict__ rw,   // (64, 2)
    const float* __restrict__ ws,   // (2, 64, 64) w_stack[t][o][d]
    const float* __restrict__ bs,   // (2, 64)
    float* __restrict__ out)        // (262144, 64)
{
    __shared__ bf16x8 sW1[8][64];   // [kt*4+ot][lane]  w1 A-frags
    __shared__ bf16x8 sWd[8][64];   // w0-w1 A-frags

    const int tid  = threadIdx.x;
    const int lane = tid & 63;
    const int wv   = tid >> 6;
    const int col  = lane & 15;
    const int q    = lane >> 4;

    const int w = blockIdx.x * 4 + wv;   // tile id, 0..16383

    // ---- x loads FIRST: HBM latency hides under the whole setup ----
    const float* xp = x + ((long)w * 16 + col) * 64 + q * 8;
    float4 xb0 = *(const float4*)xp;
    float4 xb1 = *(const float4*)(xp + 4);
    float4 xb2 = *(const float4*)(xp + 32);
    float4 xb3 = *(const float4*)(xp + 36);
    __builtin_amdgcn_sched_barrier(0);   // pin the burst at kernel entry

    // ---- setup: stage W frags (waves split the 8 (kt,ot) combos) ----
    #pragma unroll
    for (int c = wv; c < 8; c += 4) {
        const int kt = c >> 2, ot = c & 3;
        const float* p0 = ws + (ot * 16 + col) * 64 + kt * 32 + q * 8;  // w0
        const float* p1 = p0 + 4096;                                    // w1
        float4 a0 = *(const float4*)p0, a1 = *(const float4*)(p0 + 4);
        float4 c0 = *(const float4*)p1, c1 = *(const float4*)(p1 + 4);
        B8 f1, fd;
        pack8(f1, c0, c1);
        fd.u[0] = pk2bf(a0.x - c0.x, a0.y - c0.y);
        fd.u[1] = pk2bf(a0.z - c0.z, a0.w - c0.w);
        fd.u[2] = pk2bf(a1.x - c1.x, a1.y - c1.y);
        fd.u[3] = pk2bf(a1.z - c1.z, a1.w - c1.w);
        sW1[c][lane] = f1.v;
        sWd[c][lane] = fd.v;
    }

    // ---- R frags (regs), duplicated across row parity:
    // A[m][k] = rw[k][m&1] -> C rows 4q+0 / 4q+1 = (l0, l1) on EVERY lane.
    B8 R0, R1;
    {
        const int c01 = col & 1;
        float v[8];
        #pragma unroll
        for (int j = 0; j < 8; ++j)
            v[j] = rw[(q * 8 + j) * 2 + c01];
        pack8(R0, make_float4(v[0], v[1], v[2], v[3]), make_float4(v[4], v[5], v[6], v[7]));
        #pragma unroll
        for (int j = 0; j < 8; ++j)
            v[j] = rw[(32 + q * 8 + j) * 2 + c01];
        pack8(R1, make_float4(v[0], v[1], v[2], v[3]), make_float4(v[4], v[5], v[6], v[7]));
    }

    // ---- E frags + bias combos (regs, per wave) ----
    B8 E0, E1;
    {
        const float* ep = emb + col * 64 + q * 8;
        pack8(E0, *(const float4*)ep, *(const float4*)(ep + 4));
        pack8(E1, *(const float4*)(ep + 32), *(const float4*)(ep + 36));
    }
    f32x4 bI1[4], bId[4];
    #pragma unroll
    for (int ot = 0; ot < 4; ++ot) {
        float4 b1 = *(const float4*)(bs + 64 + ot * 16 + q * 4);
        float4 b0 = *(const float4*)(bs + ot * 16 + q * 4);
        bI1[ot][0] = b1.x; bI1[ot][1] = b1.y; bI1[ot][2] = b1.z; bI1[ot][3] = b1.w;
        bId[ot][0] = b0.x - b1.x; bId[ot][1] = b0.y - b1.y;
        bId[ot][2] = b0.z - b1.z; bId[ot][3] = b0.w - b1.w;
    }

    __syncthreads();  // W frags ready

    // ---- acc init via MFMA: I = b + E·W^T  (still overlapping x latency) ----
    f32x4 I1[4], Id[4], Il;
    #pragma unroll
    for (int ot = 0; ot < 4; ++ot) {
        f32x4 a1 = bI1[ot], ad = bId[ot];
        a1 = __builtin_amdgcn_mfma_f32_16x16x32_bf16(sW1[ot][lane],     E0.v, a1, 0, 0, 0);
        a1 = __builtin_amdgcn_mfma_f32_16x16x32_bf16(sW1[4 + ot][lane], E1.v, a1, 0, 0, 0);
        ad = __builtin_amdgcn_mfma_f32_16x16x32_bf16(sWd[ot][lane],     E0.v, ad, 0, 0, 0);
        ad = __builtin_amdgcn_mfma_f32_16x16x32_bf16(sWd[4 + ot][lane], E1.v, ad, 0, 0, 0);
        I1[ot] = a1;
        Id[ot] = ad;
    }
    {
        f32x4 z = {0.f, 0.f, 0.f, 0.f};
        z = __builtin_amdgcn_mfma_f32_16x16x32_bf16(R0.v, E0.v, z, 0, 0, 0);
        z = __builtin_amdgcn_mfma_f32_16x16x32_bf16(R1.v, E1.v, z, 0, 0, 0);
        Il = z;
    }

    // ---- consume the single tile ----
    B8 X0, X1;
    pack8(X0, xb0, xb1);
    pack8(X1, xb2, xb3);

    f32x4 lac = Il;
    lac = __builtin_amdgcn_mfma_f32_16x16x32_bf16(R0.v, X0.v, lac, 0, 0, 0);
    lac = __builtin_amdgcn_mfma_f32_16x16x32_bf16(R1.v, X1.v, lac, 0, 0, 0);
    // rows 4q+0 / 4q+1 hold (l0, l1) on every lane -> no shuffle
    const float att = 1.0f / (1.0f + __expf(lac[1] - lac[0]));

    const long rowoff = ((long)w * 16 + col) * 64;
    #pragma unroll
    for (int ot = 0; ot < 4; ++ot) {
        f32x4 y = I1[ot];
        y = __builtin_amdgcn_mfma_f32_16x16x32_bf16(sW1[ot][lane],     X0.v, y, 0, 0, 0);
        y = __builtin_amdgcn_mfma_f32_16x16x32_bf16(sW1[4 + ot][lane], X1.v, y, 0, 0, 0);
        f32x4 d = Id[ot];
        d = __builtin_amdgcn_mfma_f32_16x16x32_bf16(sWd[ot][lane],     X0.v, d, 0, 0, 0);
        d = __builtin_amdgcn_mfma_f32_16x16x32_bf16(sWd[4 + ot][lane], X1.v, d, 0, 0, 0);
        float4 o;
        o.x = fmaf(att, d[0], y[0]);
        o.y = fmaf(att, d[1], y[1]);
        o.z = fmaf(att, d[2], y[2]);
        o.w = fmaf(att, d[3], y[3]);
        *(float4*)(out + rowoff + ot * 16 + q * 4) = o;
    }
}

extern "C" void kernel_launch(void* const* d_in, const int* in_sizes, int n_in,
                              void* d_out, int out_size, void* d_ws, size_t ws_size,
                              hipStream_t stream) {
    const float* x   = (const float*)d_in[0];
    const float* emb = (const float*)d_in[1];
    const float* rw  = (const float*)d_in[2];
    const float* wsk = (const float*)d_in[3];
    const float* bs  = (const float*)d_in[4];
    float* out = (float*)d_out;
    sgll_kernel<<<NBLK, 256, 0, stream>>>(x, emb, rw, wsk, bs, out);
}

// Round 7
// 126.639 us; speedup vs baseline: 1.6489x; 1.4541x over previous
//
#include <hip/hip_runtime.h>

// SharedGroupLinearLayer R9 — consolidation on the session-best skeleton.
// R8 post-mortem: VGPR 40 + hbm 265MB = xb burst spilled to scratch
// (+67MB W / +40MB R); occupancy 55% at unchanged 2.8 TB/s kills the
// occupancy theory. Best-ever remains R4 (512 blk, TPW8, DEPTH4 rotating
// refill, VGPR 80): sgll <=41us. The knob tracking perf across rounds is
// sustained outstanding load-bytes per wave (depth-4 rotation ~3 tiles in
// flight continuously), not occupancy/store-merging.
// R9 = R4 exact + ONE validated delta: parity-duplicated R frags -> att
// valid on all lanes, __shfl + lgkm wait deleted from the per-step path
// (correctness proven in R5b/R6, same absmax).
//
// out[n,o] = (X w1^T + b1) + att0 * (X (w0-w1)^T + (b0-b1)),
// att0 = sigmoid(l0-l1); emb folded into acc init: C0 = b + E·W^T.

#define NBLK 512    // x 4 waves x 8 tiles x 16 tokens = 262144
#define TPW  8      // tiles per wave
#define DEPTH 4     // register pipeline depth (tiles in flight)

typedef short bf16x8 __attribute__((ext_vector_type(8)));
typedef float f32x4  __attribute__((ext_vector_type(4)));

union B8 { bf16x8 v; unsigned u[4]; };

__device__ __forceinline__ unsigned pk2bf(float lo, float hi) {
    unsigned a = __float_as_uint(lo) + 0x8000u;
    unsigned b = __float_as_uint(hi) + 0x8000u;
    return __builtin_amdgcn_perm(b, a, 0x07060302u);
}

__device__ __forceinline__ void pack8(B8& d, float4 p, float4 q) {
    d.u[0] = pk2bf(p.x, p.y); d.u[1] = pk2bf(p.z, p.w);
    d.u[2] = pk2bf(q.x, q.y); d.u[3] = pk2bf(q.z, q.w);
}

__global__ __launch_bounds__(256, 3) void sgll_kernel(
    const float* __restrict__ x,    // (262144, 64)
    const float* __restrict__ emb,  // (16, 64)  row = token % 16
    const float* __restrict__ rw,   // (64, 2)
    const float* __restrict__ ws,   // (2, 64, 64) w_stack[t][o][d]
    const float* __restrict__ bs,   // (2, 64)
    float* __restrict__ out)        // (262144, 64)
{
    __shared__ bf16x8 sW1[8][64];   // [kt*4+ot][lane]  w1 A-frags
    __shared__ bf16x8 sWd[8][64];   // w0-w1 A-frags

    const int tid  = threadIdx.x;
    const int lane = tid & 63;
    const int wv   = tid >> 6;
    const int col  = lane & 15;
    const int q    = lane >> 4;

    // ---- setup: stage W frags (waves split the 8 (kt,ot) combos) ----
    #pragma unroll
    for (int c = wv; c < 8; c += 4) {
        const int kt = c >> 2, ot = c & 3;
        const float* p0 = ws + (ot * 16 + col) * 64 + kt * 32 + q * 8;  // w0
        const float* p1 = p0 + 4096;                                    // w1
        float4 a0 = *(const float4*)p0, a1 = *(const float4*)(p0 + 4);
        float4 c0 = *(const float4*)p1, c1 = *(const float4*)(p1 + 4);
        B8 f1, fd;
        pack8(f1, c0, c1);
        fd.u[0] = pk2bf(a0.x - c0.x, a0.y - c0.y);
        fd.u[1] = pk2bf(a0.z - c0.z, a0.w - c0.w);
        fd.u[2] = pk2bf(a1.x - c1.x, a1.y - c1.y);
        fd.u[3] = pk2bf(a1.z - c1.z, a1.w - c1.w);
        sW1[c][lane] = f1.v;
        sWd[c][lane] = fd.v;
    }

    // ---- R frags (regs), duplicated across row parity:
    // A[m][k] = rw[k][m&1] -> C rows 4q+0 / 4q+1 = (l0, l1) on EVERY lane,
    // so att needs no cross-lane broadcast (validated R5b/R6).
    B8 R0, R1;
    {
        const int c01 = col & 1;
        float v[8];
        #pragma unroll
        for (int j = 0; j < 8; ++j)
            v[j] = rw[(q * 8 + j) * 2 + c01];
        pack8(R0, make_float4(v[0], v[1], v[2], v[3]), make_float4(v[4], v[5], v[6], v[7]));
        #pragma unroll
        for (int j = 0; j < 8; ++j)
            v[j] = rw[(32 + q * 8 + j) * 2 + c01];
        pack8(R1, make_float4(v[0], v[1], v[2], v[3]), make_float4(v[4], v[5], v[6], v[7]));
    }

    // ---- E frags + bias combos (regs, per wave) ----
    B8 E0, E1;
    {
        const float* ep = emb + col * 64 + q * 8;
        pack8(E0, *(const float4*)ep, *(const float4*)(ep + 4));
        pack8(E1, *(const float4*)(ep + 32), *(const float4*)(ep + 36));
    }
    f32x4 bI1[4], bId[4];
    #pragma unroll
    for (int ot = 0; ot < 4; ++ot) {
        float4 b1 = *(const float4*)(bs + 64 + ot * 16 + q * 4);
        float4 b0 = *(const float4*)(bs + ot * 16 + q * 4);
        bI1[ot][0] = b1.x; bI1[ot][1] = b1.y; bI1[ot][2] = b1.z; bI1[ot][3] = b1.w;
        bId[ot][0] = b0.x - b1.x; bId[ot][1] = b0.y - b1.y;
        bId[ot][2] = b0.z - b1.z; bId[ot][3] = b0.w - b1.w;
    }

    __syncthreads();  // W frags ready

    // ---- prologue: fill the pipeline (DEPTH tiles = 16 dwordx4 in flight) ----
    const long base = (long)(blockIdx.x * 4 + wv) * (TPW * 16);   // first token
    float4 buf[DEPTH][4];
    #pragma unroll
    for (int t = 0; t < DEPTH; ++t) {
        const float* p = x + (base + (long)t * 16 + col) * 64 + q * 8;
        buf[t][0] = *(const float4*)p;        buf[t][1] = *(const float4*)(p + 4);
        buf[t][2] = *(const float4*)(p + 32); buf[t][3] = *(const float4*)(p + 36);
    }
    __builtin_amdgcn_sched_barrier(0);   // pin the burst before compute

    // ---- acc init via MFMA (overlaps prologue load latency) ----
    f32x4 I1[4], Id[4], Il;
    #pragma unroll
    for (int ot = 0; ot < 4; ++ot) {
        f32x4 a1 = bI1[ot], ad = bId[ot];
        a1 = __builtin_amdgcn_mfma_f32_16x16x32_bf16(sW1[ot][lane],     E0.v, a1, 0, 0, 0);
        a1 = __builtin_amdgcn_mfma_f32_16x16x32_bf16(sW1[4 + ot][lane], E1.v, a1, 0, 0, 0);
        ad = __builtin_amdgcn_mfma_f32_16x16x32_bf16(sWd[ot][lane],     E0.v, ad, 0, 0, 0);
        ad = __builtin_amdgcn_mfma_f32_16x16x32_bf16(sWd[4 + ot][lane], E1.v, ad, 0, 0, 0);
        I1[ot] = a1;
        Id[ot] = ad;
    }
    {
        f32x4 z = {0.f, 0.f, 0.f, 0.f};
        z = __builtin_amdgcn_mfma_f32_16x16x32_bf16(R0.v, E0.v, z, 0, 0, 0);
        z = __builtin_amdgcn_mfma_f32_16x16x32_bf16(R1.v, E1.v, z, 0, 0, 0);
        Il = z;
    }

    // ---- steady state: consume tile i, refill slot with tile i+DEPTH ----
    #pragma unroll
    for (int i = 0; i < TPW; ++i) {
        const int b = i & (DEPTH - 1);

        B8 X0, X1;
        pack8(X0, buf[b][0], buf[b][1]);
        pack8(X1, buf[b][2], buf[b][3]);

        // refill the slot immediately after the consume reads (keeps queue full)
        if (i + DEPTH < TPW) {
            const float* p = x + (base + (long)(i + DEPTH) * 16 + col) * 64 + q * 8;
            buf[b][0] = *(const float4*)p;        buf[b][1] = *(const float4*)(p + 4);
            buf[b][2] = *(const float4*)(p + 32); buf[b][3] = *(const float4*)(p + 36);
        }

        f32x4 lac = Il;
        lac = __builtin_amdgcn_mfma_f32_16x16x32_bf16(R0.v, X0.v, lac, 0, 0, 0);
        lac = __builtin_amdgcn_mfma_f32_16x16x32_bf16(R1.v, X1.v, lac, 0, 0, 0);
        // rows 4q+0 / 4q+1 hold (l0, l1) on every lane -> no shuffle
        const float att = 1.0f / (1.0f + __expf(lac[1] - lac[0]));

        const long rowoff = (base + (long)i * 16 + col) * 64;
        #pragma unroll
        for (int ot = 0; ot < 4; ++ot) {
            f32x4 y = I1[ot];
            y = __builtin_amdgcn_mfma_f32_16x16x32_bf16(sW1[ot][lane],     X0.v, y, 0, 0, 0);
            y = __builtin_amdgcn_mfma_f32_16x16x32_bf16(sW1[4 + ot][lane], X1.v, y, 0, 0, 0);
            f32x4 d = Id[ot];
            d = __builtin_amdgcn_mfma_f32_16x16x32_bf16(sWd[ot][lane],     X0.v, d, 0, 0, 0);
            d = __builtin_amdgcn_mfma_f32_16x16x32_bf16(sWd[4 + ot][lane], X1.v, d, 0, 0, 0);
            float4 o;
            o.x = fmaf(att, d[0], y[0]);
            o.y = fmaf(att, d[1], y[1]);
            o.z = fmaf(att, d[2], y[2]);
            o.w = fmaf(att, d[3], y[3]);
            *(float4*)(out + rowoff + ot * 16 + q * 4) = o;   // 16B coalesced
        }
    }
}

extern "C" void kernel_launch(void* const* d_in, const int* in_sizes, int n_in,
                              void* d_out, int out_size, void* d_ws, size_t ws_size,
                              hipStream_t stream) {
    const float* x   = (const float*)d_in[0];
    const float* emb = (const float*)d_in[1];
    const float* rw  = (const float*)d_in[2];
    const float* wsk = (const float*)d_in[3];
    const float* bs  = (const float*)d_in[4];
    float* out = (float*)d_out;
    sgll_kernel<<<NBLK, 256, 0, stream>>>(x, emb, rw, wsk, bs, out);
}